// Round 3
// baseline (473.871 us; speedup 1.0000x reference)
//
#include <hip/hip_runtime.h>
#include <hip/hip_bf16.h>
#include <cstdio>
#include <cstdint>

// N=16, C=128, HW=16384, Cr=64, M=128
#define HWD 16384
#define NB  16
#define CD  128
#define CR  64
#define MF  128

constexpr float K_AMP = 2.4494897427831781f;   // sqrt(6)
constexpr float DN    = 0.35355339059327379f;  // 64^-0.25
constexpr float RATIO = 0.088388347648318447f; // 128^-0.5
constexpr float EPSN  = 5e-5f;
constexpr float EPSK  = 1e-4f;
constexpr float RES   = 0.1f;
constexpr float DIAG  = 0.375f;  // ||k||^2=6 after l2norm => kdiag = 0.5*6*dn^2 exactly

typedef __attribute__((ext_vector_type(4))) float f32x4;
typedef __attribute__((ext_vector_type(8))) short s16x8;

__device__ __forceinline__ short f2bf(float f) {
  __hip_bfloat16 h = __float2bfloat16(f);
  short s; __builtin_memcpy(&s, &h, 2); return s;
}
__device__ __forceinline__ float bf2f_s(short s) {
  __hip_bfloat16 h; __builtin_memcpy(&h, &s, 2); return __bfloat162float(h);
}
__device__ __forceinline__ f32x4 mfma16(s16x8 a, s16x8 b, f32x4 c) {
  return __builtin_amdgcn_mfma_f32_16x16x32_bf16(a, b, c, 0, 0, 0);
}

// ---- workspace layout (float offsets) ----
constexpr size_t OFF_QP   = 0;                          // bf16 [N][HW][M]
constexpr size_t OFF_EP   = OFF_QP   + 16777216;        // bf16 e' [N][HW][M]
constexpr size_t OFF_GP   = OFF_EP   + 16777216;        // fp32 [32][N][M][C]
constexpr size_t OFF_G    = OFF_GP   + 8388608;         // fp32 [N][M][C]
constexpr size_t OFF_CTXB = OFF_G    + 262144;          // bf16 [N][C][M]
constexpr size_t OFF_KSUM = OFF_CTXB + 131072;          // fp32 [N][M]
constexpr size_t OFF_XSUM = OFF_KSUM + 2048;            // fp32 [N][C]
constexpr size_t OFF_KSUMB= OFF_XSUM + 2048;            // fp32 [N][128][M]
constexpr size_t OFF_XSUMB= OFF_KSUMB+ 262144;          // fp32 [N][128][C]
constexpr size_t OFF_BMAX = OFF_XSUMB+ 262144;          // fp32 [N][128]
constexpr size_t OFF_SBLK = OFF_BMAX + 2048;            // fp32 [N][128]
constexpr size_t OFF_W1B  = OFF_SBLK + 2048;            // bf16 [64][128]
constexpr size_t OFF_W2B  = OFF_W1B  + 4096;
constexpr size_t OFF_PB   = OFF_W2B  + 4096;            // bf16 [128][64]
constexpr size_t WS_FLOATS = OFF_PB  + 4096;

// ---- weights -> bf16 ----
__global__ void k_prep(const float* __restrict__ w1, const float* __restrict__ w2,
                       const float* __restrict__ proj,
                       short* __restrict__ w1b, short* __restrict__ w2b, short* __restrict__ pb) {
  int t = blockIdx.x * 256 + threadIdx.x;   // 8192 threads; all three are 8192 elems
  w1b[t] = f2bf(w1[t]);
  w2b[t] = f2bf(w2[t]);
  pb[t]  = f2bf(proj[t]);
}

// GEMM1 (W·X + bias + l2norm -> Qt) then GEMM2 (Qt·P^T -> acc2). Shared by Q and K phases.
// Qt rows are WAVE-PRIVATE (wave w writes+reads rows [w*32, w*32+32) only) -> no barriers.
__device__ __forceinline__ void qk_gemms(const short* __restrict__ wb,
                                         const float* __restrict__ bsh,
                                         const short* __restrict__ pb,
                                         const short* Xt, short* Qt,
                                         int tid, f32x4 (&acc2)[8][2]) {
  const int lane = tid & 63, w = tid >> 6;
  const int l15 = lane & 15, q4 = lane >> 4;
  f32x4 acc1[4][2];
  #pragma unroll
  for (int ct = 0; ct < 4; ct++)
    #pragma unroll
    for (int it = 0; it < 2; it++) acc1[ct][it] = {0.f, 0.f, 0.f, 0.f};
  #pragma unroll
  for (int ks = 0; ks < 4; ks++) {
    s16x8 bfr[2];
    #pragma unroll
    for (int it = 0; it < 2; it++)
      bfr[it] = *(const s16x8*)&Xt[(w * 32 + it * 16 + l15) * 136 + ks * 32 + q4 * 8];
    #pragma unroll
    for (int ct = 0; ct < 4; ct++) {
      s16x8 afr = *(const s16x8*)&wb[(ct * 16 + l15) * 128 + ks * 32 + q4 * 8];
      #pragma unroll
      for (int it = 0; it < 2; it++) acc1[ct][it] = mfma16(afr, bfr[it], acc1[ct][it]);
    }
  }
  // bias + l2norm: lane holds c = ct*16+q4*4+r, i = it*16+l15 (+w*32)
  float qv[4][2][4];
  float ss[2] = {0.f, 0.f};
  #pragma unroll
  for (int ct = 0; ct < 4; ct++)
    #pragma unroll
    for (int it = 0; it < 2; it++)
      #pragma unroll
      for (int r = 0; r < 4; r++) {
        float v = acc1[ct][it][r] + bsh[ct * 16 + q4 * 4 + r];
        qv[ct][it][r] = v;
        ss[it] = fmaf(v, v, ss[it]);
      }
  #pragma unroll
  for (int it = 0; it < 2; it++) {
    ss[it] += __shfl_xor(ss[it], 16);
    ss[it] += __shfl_xor(ss[it], 32);
  }
  float scale[2];
  #pragma unroll
  for (int it = 0; it < 2; it++)
    scale[it] = (K_AMP * DN) / fmaxf(sqrtf(ss[it]), EPSN);
  // wave-private Qt write (no barrier needed; lgkmcnt orders within-wave RAW)
  #pragma unroll
  for (int it = 0; it < 2; it++)
    #pragma unroll
    for (int ct = 0; ct < 4; ct++) {
      short4 pk;
      pk.x = f2bf(qv[ct][it][0] * scale[it]);
      pk.y = f2bf(qv[ct][it][1] * scale[it]);
      pk.z = f2bf(qv[ct][it][2] * scale[it]);
      pk.w = f2bf(qv[ct][it][3] * scale[it]);
      *(short4*)&Qt[(w * 32 + it * 16 + l15) * 72 + ct * 16 + q4 * 4] = pk;
    }
  // GEMM2: QD[i=128][m=128] = Q' · P^T ; wave w: i in [w*32,+32) x all m
  #pragma unroll
  for (int mt = 0; mt < 8; mt++)
    #pragma unroll
    for (int it = 0; it < 2; it++) acc2[mt][it] = {0.f, 0.f, 0.f, 0.f};
  #pragma unroll
  for (int ks = 0; ks < 2; ks++) {
    s16x8 afr[2];
    #pragma unroll
    for (int it = 0; it < 2; it++)
      afr[it] = *(const s16x8*)&Qt[(w * 32 + it * 16 + l15) * 72 + ks * 32 + q4 * 8];
    #pragma unroll
    for (int mt = 0; mt < 8; mt++) {
      s16x8 bfr = *(const s16x8*)&pb[(mt * 16 + l15) * 64 + ks * 32 + q4 * 8];
      #pragma unroll
      for (int it = 0; it < 2; it++) acc2[mt][it] = mfma16(afr[it], bfr, acc2[mt][it]);
    }
  }
}

// Fused feature path: stage X once; Q phase -> qp; K phase -> e'=exp(kd-bm) bf16
// + per-block bmax, esum[m], xsum[c] partials. Global-max rescale deferred to k_g/k_ksum.
// LDS: Xt 34816 + (Qt|sred) 18432 + bsh 512 + wred 16 = 53776 B -> 3 blocks/CU.
__global__ __launch_bounds__(256) void k_qkf(
    const float* __restrict__ x,
    const short* __restrict__ w1b, const float* __restrict__ b1,
    const short* __restrict__ w2b, const float* __restrict__ b2,
    const short* __restrict__ pb,
    short* __restrict__ qp, short* __restrict__ ep,
    float* __restrict__ bmax, float* __restrict__ ksumb, float* __restrict__ xsumb) {
  const int n = blockIdx.y, i0 = blockIdx.x * 128;
  const int tid = threadIdx.x, lane = tid & 63, w = tid >> 6;
  const int l15 = lane & 15, q4 = lane >> 4;
  __shared__ __align__(16) short Xt[128 * 136];  // [i][c]
  __shared__ __align__(16) char smemQ[128 * 72 * 2];  // Qt [i][cr]; reused as sred[768] floats
  __shared__ float bsh[128];                     // b1 | b2
  __shared__ float wred[4];
  short* Qt = (short*)smemQ;
  float* sred = (float*)smemQ;   // [0..511] esum per (w,m); [512..767] xsum partials
  if (tid < 64) bsh[tid] = b1[tid];
  else if (tid < 128) bsh[tid] = b2[tid - 64];
  // stage Xt[i][c] bf16 (transpose: 4 c per thread-read, same i)
  #pragma unroll
  for (int u = 0; u < 16; u++) {
    int id = u * 256 + tid;
    int i = id & 127, cg = id >> 7;            // cg 0..31
    const float* xp = x + ((size_t)(n * CD + cg * 4) * HWD + i0 + i);
    short4 pk;
    pk.x = f2bf(xp[0]); pk.y = f2bf(xp[HWD]);
    pk.z = f2bf(xp[2 * HWD]); pk.w = f2bf(xp[3 * HWD]);
    *(short4*)&Xt[i * 136 + cg * 4] = pk;
  }
  __syncthreads();

  f32x4 acc2[8][2];

  // ===== Q phase =====
  qk_gemms(w1b, bsh, pb, Xt, Qt, tid, acc2);
  // D-tile: i = i0 + w*32 + it*16 + q4*4 + r ; m = mt*16 + l15
  #pragma unroll
  for (int it = 0; it < 2; it++)
    #pragma unroll
    for (int r = 0; r < 4; r++) {
      float mx = -3.0e38f;
      #pragma unroll
      for (int mt = 0; mt < 8; mt++) mx = fmaxf(mx, acc2[mt][it][r]);
      mx = fmaxf(mx, __shfl_xor(mx, 1));
      mx = fmaxf(mx, __shfl_xor(mx, 2));
      mx = fmaxf(mx, __shfl_xor(mx, 4));
      mx = fmaxf(mx, __shfl_xor(mx, 8));
      int i = i0 + w * 32 + it * 16 + q4 * 4 + r;
      #pragma unroll
      for (int mt = 0; mt < 8; mt++) {
        float e = RATIO * (__expf(acc2[mt][it][r] - DIAG - mx) + EPSK);
        qp[((size_t)n * HWD + i) * MF + mt * 16 + l15] = f2bf(e);
      }
    }

  // ===== K phase =====
  qk_gemms(w2b, bsh + 64, pb, Xt, Qt, tid, acc2);
  // block max
  float mxk = -3.0e38f;
  #pragma unroll
  for (int mt = 0; mt < 8; mt++)
    #pragma unroll
    for (int it = 0; it < 2; it++)
      #pragma unroll
      for (int r = 0; r < 4; r++) mxk = fmaxf(mxk, acc2[mt][it][r]);
  #pragma unroll
  for (int d = 1; d < 64; d <<= 1) mxk = fmaxf(mxk, __shfl_xor(mxk, d));
  if (lane == 0) wred[w] = mxk;
  __syncthreads();  // all waves past GEMM2 Qt reads -> sred may overwrite Qt
  const float bm = fmaxf(fmaxf(wred[0], wred[1]), fmaxf(wred[2], wred[3]));
  float es[8];
  #pragma unroll
  for (int mt = 0; mt < 8; mt++) es[mt] = 0.f;
  #pragma unroll
  for (int it = 0; it < 2; it++)
    #pragma unroll
    for (int r = 0; r < 4; r++) {
      int i = i0 + w * 32 + it * 16 + q4 * 4 + r;
      #pragma unroll
      for (int mt = 0; mt < 8; mt++) {
        float e = __expf(acc2[mt][it][r] - bm);   // e' in (0,1]; DIAG folded into sblk
        es[mt] += e;
        ep[((size_t)n * HWD + i) * MF + mt * 16 + l15] = f2bf(e);
      }
    }
  // reduce es over q4 (i-coverage of the wave); lanes with q4==0 hold per-(w,m) partials
  #pragma unroll
  for (int mt = 0; mt < 8; mt++) {
    es[mt] += __shfl_xor(es[mt], 16);
    es[mt] += __shfl_xor(es[mt], 32);
  }
  if (q4 == 0) {
    #pragma unroll
    for (int mt = 0; mt < 8; mt++) sred[w * 128 + mt * 16 + l15] = es[mt];
  }
  // xsum partial over staged Xt: thread -> (c = tid&127, half), 64 i each
  {
    int c = tid & 127, half = tid >> 7;
    float xs = 0.f;
    #pragma unroll 16
    for (int u = 0; u < 64; u++) xs += bf2f_s(Xt[(half * 64 + u) * 136 + c]);
    sred[512 + tid] = xs;
  }
  __syncthreads();
  const size_t pb0 = ((size_t)n * 128 + blockIdx.x) * 128;
  if (tid < 128) {
    ksumb[pb0 + tid] = sred[tid] + sred[128 + tid] + sred[256 + tid] + sred[384 + tid];
  } else {
    int c = tid - 128;
    xsumb[pb0 + c] = sred[512 + c] + sred[640 + c];
  }
  if (tid == 0) bmax[n * 128 + blockIdx.x] = bm;
}

// Merged: global key max (redundant per block) + sblk + ksum + xsum.
// sblk_b = RATIO * exp(bmax_b - gm - DIAG);
// ksum[n][m] = sum_b sblk_b * esum_b[m] + ratio*eps*HW ; xsum[n][c] = sum_b xsum_b[c]
__global__ void k_ksum(const float* __restrict__ bmax, const float* __restrict__ ksumb,
                       const float* __restrict__ xsumb, float* __restrict__ sblk,
                       float* __restrict__ ksum, float* __restrict__ xsum) {
  __shared__ float red[256];
  __shared__ float sb_sh[256];
  int t = threadIdx.x;
  float v = -3.0e38f;
  #pragma unroll
  for (int u = 0; u < 8; u++) v = fmaxf(v, bmax[t + 256 * u]);
  red[t] = v;
  __syncthreads();
  for (int s = 128; s > 0; s >>= 1) {
    if (t < s) red[t] = fmaxf(red[t], red[t + s]);
    __syncthreads();
  }
  const float gm = red[0];
  int g = blockIdx.x * 256 + t;   // 0..2047 ; block covers 2 consecutive n
  int n = g >> 7, m = g & 127;
  float sv = RATIO * __expf(bmax[g] - gm - DIAG);
  sb_sh[t] = sv;
  sblk[g] = sv;
  __syncthreads();
  const float* kb = ksumb + ((size_t)n << 14) + m;
  const float* xb = xsumb + ((size_t)n << 14) + m;
  const float* sb = &sb_sh[(t >> 7) * 128];
  float s = 0.f, xs = 0.f;
  #pragma unroll 4
  for (int b = 0; b < 128; b++) {
    s = fmaf(sb[b], kb[(size_t)b * 128], s);
    xs += xb[(size_t)b * 128];
  }
  ksum[g] = s + RATIO * EPSK * 16384.0f;
  xsum[g] = xs;
}

// G partials: Gp[slab][n][m][c] = sum_{i in slab} e'[i][m] * (sblk*x)[c][i]  (K=512/block)
__global__ __launch_bounds__(256) void k_g(const float* __restrict__ x,
                                           const short* __restrict__ ep,
                                           const float* __restrict__ sblk,
                                           float* __restrict__ gp) {
  const int slab = blockIdx.x, n = blockIdx.y;
  const int t = threadIdx.x, lane = t & 63, w = t >> 6;
  const int l15 = lane & 15, q4 = lane >> 4;
  __shared__ short kl[64 * 136];   // [i][m]  (e' bf16)
  __shared__ short xl[128 * 72];   // [c][i]  (pre-scaled by sblk)
  f32x4 acc[2][8];
  #pragma unroll
  for (int mt = 0; mt < 2; mt++)
    #pragma unroll
    for (int ct = 0; ct < 8; ct++) acc[mt][ct] = {0.f, 0.f, 0.f, 0.f};
  for (int ch = 0; ch < 8; ch++) {
    int ib = slab * 512 + ch * 64;
    const float sf = sblk[n * 128 + slab * 4 + (ch >> 1)];  // uniform per 64-i chunk
    __syncthreads();
    #pragma unroll
    for (int u = 0; u < 4; u++) {                   // e' chunk [64 i][128 m]
      int id = u * 256 + t, ii = id >> 4, m8 = (id & 15) * 8;
      *(s16x8*)&kl[ii * 136 + m8] =
          *(const s16x8*)&ep[((size_t)n * HWD + ib + ii) * MF + m8];
    }
    #pragma unroll
    for (int u = 0; u < 8; u++) {                   // x chunk [128 c][64 i], scaled
      int id = u * 256 + t, c = id >> 4, i4 = (id & 15) * 4;
      const float4 v = *(const float4*)(x + ((size_t)n * CD + c) * HWD + ib + i4);
      short4 pk;
      pk.x = f2bf(v.x * sf); pk.y = f2bf(v.y * sf);
      pk.z = f2bf(v.z * sf); pk.w = f2bf(v.w * sf);
      *(short4*)&xl[c * 72 + i4] = pk;
    }
    __syncthreads();
    #pragma unroll
    for (int ks = 0; ks < 2; ks++) {
      s16x8 afr[2];
      #pragma unroll
      for (int mt = 0; mt < 2; mt++) {              // transpose-read e': A[m][k=i]
        int m = w * 32 + mt * 16 + l15;
        short tmp[8];
        #pragma unroll
        for (int j = 0; j < 8; j++) tmp[j] = kl[(ks * 32 + q4 * 8 + j) * 136 + m];
        afr[mt] = *(s16x8*)tmp;
      }
      #pragma unroll
      for (int ct = 0; ct < 8; ct++) {
        s16x8 bfr = *(const s16x8*)&xl[(ct * 16 + l15) * 72 + ks * 32 + q4 * 8];
        #pragma unroll
        for (int mt = 0; mt < 2; mt++) acc[mt][ct] = mfma16(afr[mt], bfr, acc[mt][ct]);
      }
    }
  }
  float* g = gp + (((size_t)slab * NB + n) << 14);
  #pragma unroll
  for (int mt = 0; mt < 2; mt++)
    #pragma unroll
    for (int ct = 0; ct < 8; ct++)
      #pragma unroll
      for (int r = 0; r < 4; r++)
        g[(w * 32 + mt * 16 + q4 * 4 + r) * CD + ct * 16 + l15] = acc[mt][ct][r];
}

__global__ void k_gred(const float* __restrict__ gp, const float* __restrict__ xsum,
                       float* __restrict__ G) {
  int t = blockIdx.x * 256 + threadIdx.x;   // 262144
  int n = t >> 14, r = t & 16383;
  float s = 0.f;
  #pragma unroll
  for (int sc = 0; sc < 32; sc++) s += gp[(((size_t)sc * NB + n) << 14) + r];
  G[((size_t)n << 14) + r] = s + (RATIO * EPSK) * xsum[n * 128 + (r & 127)];
}

// ctx[m][c] = sum_c2 wa[c][c2]*G[m][c2] + ba[c]*ksum[m]; writes ctx^T bf16 [c][m]
__global__ __launch_bounds__(256) void k_ctx(const float* __restrict__ G,
                                             const float* __restrict__ wa,
                                             const float* __restrict__ ba,
                                             const float* __restrict__ ksum,
                                             short* __restrict__ ctxb) {
  int n = blockIdx.x;
  int tm = threadIdx.x & 15, tc = threadIdx.x >> 4;
  const float* Gn = G + ((size_t)n << 14);
  float acc[8][8];
  #pragma unroll
  for (int a = 0; a < 8; a++)
    #pragma unroll
    for (int b = 0; b < 8; b++) acc[a][b] = 0.f;
  for (int c2 = 0; c2 < CD; c2 += 4) {
    float4 g4[8], w4[8];
    #pragma unroll
    for (int a = 0; a < 8; a++) g4[a] = *(const float4*)&Gn[(tm * 8 + a) * CD + c2];
    #pragma unroll
    for (int b = 0; b < 8; b++) w4[b] = *(const float4*)&wa[(tc * 8 + b) * CD + c2];
    #pragma unroll
    for (int a = 0; a < 8; a++)
      #pragma unroll
      for (int b = 0; b < 8; b++) {
        acc[a][b] = fmaf(g4[a].x, w4[b].x, acc[a][b]);
        acc[a][b] = fmaf(g4[a].y, w4[b].y, acc[a][b]);
        acc[a][b] = fmaf(g4[a].z, w4[b].z, acc[a][b]);
        acc[a][b] = fmaf(g4[a].w, w4[b].w, acc[a][b]);
      }
  }
  #pragma unroll
  for (int a = 0; a < 8; a++) {
    int m = tm * 8 + a;
    float km = ksum[n * MF + m];
    #pragma unroll
    for (int b = 0; b < 8; b++) {
      int c = tc * 8 + b;
      ctxb[((size_t)n * CD + c) * MF + m] = f2bf(acc[a][b] + ba[c] * km);
    }
  }
}

// out[c][i] = dinv[i] * sum_m ctx^T[c][m] * qp[i][m] ; dinv = RES / (qp·ksum)
__global__ __launch_bounds__(256) void k_out(const short* __restrict__ qp,
                                             const short* __restrict__ ctxb,
                                             const float* __restrict__ ksum,
                                             float* __restrict__ out) {
  const int n = blockIdx.y, i0 = blockIdx.x * 128;
  const int t = threadIdx.x, lane = t & 63, w = t >> 6;
  const int l15 = lane & 15, q4 = lane >> 4;
  __shared__ short qt[128 * 136];  // [i][m]
  __shared__ float ksl[128];
  __shared__ float dinv[128];
  if (t < 128) ksl[t] = ksum[n * MF + t];
  #pragma unroll
  for (int u = 0; u < 8; u++) {
    int id = u * 256 + t, i = id >> 4, m8 = (id & 15) * 8;
    *(s16x8*)&qt[i * 136 + m8] =
        *(const s16x8*)&qp[((size_t)n * HWD + i0 + i) * MF + m8];
  }
  __syncthreads();
  if (t < 128) {
    float s = 0.f;
    #pragma unroll
    for (int mb = 0; mb < 16; mb++) {
      s16x8 v = *(const s16x8*)&qt[t * 136 + mb * 8];
      #pragma unroll
      for (int j = 0; j < 8; j++) s = fmaf(bf2f_s(v[j]), ksl[mb * 8 + j], s);
    }
    dinv[t] = RES / s;
  }
  f32x4 acc[8][2];
  #pragma unroll
  for (int it = 0; it < 8; it++)
    #pragma unroll
    for (int ct = 0; ct < 2; ct++) acc[it][ct] = {0.f, 0.f, 0.f, 0.f};
  #pragma unroll
  for (int ks = 0; ks < 4; ks++) {
    s16x8 afr[2];
    #pragma unroll
    for (int ct = 0; ct < 2; ct++)
      afr[ct] = *(const s16x8*)&ctxb[((size_t)n * CD + w * 32 + ct * 16 + l15) * MF +
                                     ks * 32 + q4 * 8];
    #pragma unroll
    for (int it = 0; it < 8; it++) {
      s16x8 bfr = *(const s16x8*)&qt[(it * 16 + l15) * 136 + ks * 32 + q4 * 8];
      #pragma unroll
      for (int ct = 0; ct < 2; ct++) acc[it][ct] = mfma16(afr[ct], bfr, acc[it][ct]);
    }
  }
  __syncthreads();  // dinv ready
  #pragma unroll
  for (int it = 0; it < 8; it++) {
    float dv = dinv[it * 16 + l15];
    #pragma unroll
    for (int ct = 0; ct < 2; ct++)
      #pragma unroll
      for (int r = 0; r < 4; r++)
        out[((size_t)n * CD + w * 32 + ct * 16 + q4 * 4 + r) * HWD + i0 + it * 16 + l15] =
            acc[it][ct][r] * dv;
  }
}

extern "C" void kernel_launch(void* const* d_in, const int* in_sizes, int n_in,
                              void* d_out, int out_size, void* d_ws, size_t ws_size,
                              hipStream_t stream) {
  (void)in_sizes; (void)n_in; (void)out_size;
  const float* x    = (const float*)d_in[0];
  const float* w1   = (const float*)d_in[1];
  const float* b1   = (const float*)d_in[2];
  const float* w2   = (const float*)d_in[3];
  const float* b2   = (const float*)d_in[4];
  const float* wa   = (const float*)d_in[5];
  const float* ba   = (const float*)d_in[6];
  const float* proj = (const float*)d_in[7];
  float* ws  = (float*)d_ws;
  float* out = (float*)d_out;

  if (ws_size < WS_FLOATS * sizeof(float)) {
    fprintf(stderr, "ENLCA: workspace too small: need %zu, have %zu\n",
            WS_FLOATS * sizeof(float), ws_size);
  }

  short* qpB   = (short*)(ws + OFF_QP);
  short* epB   = (short*)(ws + OFF_EP);
  float* gpF   = ws + OFF_GP;
  float* GF    = ws + OFF_G;
  short* ctxB  = (short*)(ws + OFF_CTXB);
  float* ksumF = ws + OFF_KSUM;
  float* xsumF = ws + OFF_XSUM;
  float* ksumbF= ws + OFF_KSUMB;
  float* xsumbF= ws + OFF_XSUMB;
  float* bmaxF = ws + OFF_BMAX;
  float* sblkF = ws + OFF_SBLK;
  short* w1B   = (short*)(ws + OFF_W1B);
  short* w2B   = (short*)(ws + OFF_W2B);
  short* pB    = (short*)(ws + OFF_PB);

  k_prep<<<32, 256, 0, stream>>>(w1, w2, proj, w1B, w2B, pB);
  k_qkf<<<dim3(128, 16), 256, 0, stream>>>(x, w1B, b1, w2B, b2, pB,
                                           qpB, epB, bmaxF, ksumbF, xsumbF);
  k_ksum<<<8, 256, 0, stream>>>(bmaxF, ksumbF, xsumbF, sblkF, ksumF, xsumF);
  k_g<<<dim3(32, 16), 256, 0, stream>>>(x, epB, sblkF, gpF);
  k_gred<<<1024, 256, 0, stream>>>(gpF, xsumF, GF);
  k_ctx<<<16, 256, 0, stream>>>(GF, wa, ba, ksumF, ctxB);
  k_out<<<dim3(128, 16), 256, 0, stream>>>(qpB, ctxB, ksumF, out);
}

// Round 8
// 466.815 us; speedup vs baseline: 1.0151x; 1.0151x over previous
//
#include <hip/hip_runtime.h>
#include <hip/hip_bf16.h>
#include <cstdio>
#include <cstdint>

// N=16, C=128, HW=16384, Cr=64, M=128
#define HWD 16384
#define NB  16
#define CD  128
#define CR  64
#define MF  128

constexpr float K_AMP = 2.4494897427831781f;   // sqrt(6)
constexpr float DN    = 0.35355339059327379f;  // 64^-0.25
constexpr float RATIO = 0.088388347648318447f; // 128^-0.5
constexpr float EPSN  = 5e-5f;
constexpr float EPSK  = 1e-4f;
constexpr float RES   = 0.1f;
constexpr float DIAG  = 0.375f;  // ||k||^2=6 after l2norm => kdiag = 0.5*6*dn^2 exactly

typedef __attribute__((ext_vector_type(4))) float f32x4;
typedef __attribute__((ext_vector_type(8))) short s16x8;

__device__ __forceinline__ short f2bf(float f) {
  __hip_bfloat16 h = __float2bfloat16(f);
  short s; __builtin_memcpy(&s, &h, 2); return s;
}
__device__ __forceinline__ float bf2f_s(short s) {
  __hip_bfloat16 h; __builtin_memcpy(&h, &s, 2); return __bfloat162float(h);
}
__device__ __forceinline__ f32x4 mfma16(s16x8 a, s16x8 b, f32x4 c) {
  return __builtin_amdgcn_mfma_f32_16x16x32_bf16(a, b, c, 0, 0, 0);
}

// ---- workspace layout (float offsets) ----
constexpr size_t OFF_QP   = 0;                          // bf16 [N][HW][M]
constexpr size_t OFF_EP   = OFF_QP   + 16777216;        // bf16 e' [N][HW][M]
constexpr size_t OFF_GP   = OFF_EP   + 16777216;        // fp32 [32][N][M][C]
constexpr size_t OFF_G    = OFF_GP   + 8388608;         // fp32 [N][M][C]
constexpr size_t OFF_CTXB = OFF_G    + 262144;          // bf16 [N][C][M]
constexpr size_t OFF_KSUM = OFF_CTXB + 131072;          // fp32 [N][M]
constexpr size_t OFF_XSUM = OFF_KSUM + 2048;            // fp32 [N][C]
constexpr size_t OFF_KSUMB= OFF_XSUM + 2048;            // fp32 [N][128][M]
constexpr size_t OFF_XSUMB= OFF_KSUMB+ 262144;          // fp32 [N][128][C]
constexpr size_t OFF_BMAX = OFF_XSUMB+ 262144;          // fp32 [N][128]
constexpr size_t OFF_SBLK = OFF_BMAX + 2048;            // fp32 [N][128]
constexpr size_t OFF_W1B  = OFF_SBLK + 2048;            // bf16 [64][128]
constexpr size_t OFF_W2B  = OFF_W1B  + 4096;
constexpr size_t OFF_PB   = OFF_W2B  + 4096;            // bf16 [128][64]
constexpr size_t WS_FLOATS = OFF_PB  + 4096;

// ---- weights -> bf16 ----
__global__ void k_prep(const float* __restrict__ w1, const float* __restrict__ w2,
                       const float* __restrict__ proj,
                       short* __restrict__ w1b, short* __restrict__ w2b, short* __restrict__ pb) {
  int t = blockIdx.x * 256 + threadIdx.x;   // 8192 threads; all three are 8192 elems
  w1b[t] = f2bf(w1[t]);
  w2b[t] = f2bf(w2[t]);
  pb[t]  = f2bf(proj[t]);
}

// GEMM1 (W·X + bias + l2norm -> Qt) then GEMM2 (Qt·P^T -> acc2). Shared by Q and K phases.
// NOTE: barriers around the Qt write are kept deliberately — removing them let the
// compiler inflate VGPR 108->132 (crossing the 128 wave-budget boundary) and cost
// 16 us (round-3 regression). Do not remove without checking VGPR_Count.
__device__ __forceinline__ void qk_gemms(const short* __restrict__ wb,
                                         const float* __restrict__ bsh,
                                         const short* __restrict__ pb,
                                         const short* Xt, short* Qt,
                                         int tid, f32x4 (&acc2)[8][2]) {
  const int lane = tid & 63, w = tid >> 6;
  const int l15 = lane & 15, q4 = lane >> 4;
  f32x4 acc1[4][2];
  #pragma unroll
  for (int ct = 0; ct < 4; ct++)
    #pragma unroll
    for (int it = 0; it < 2; it++) acc1[ct][it] = {0.f, 0.f, 0.f, 0.f};
  #pragma unroll
  for (int ks = 0; ks < 4; ks++) {
    s16x8 bfr[2];
    #pragma unroll
    for (int it = 0; it < 2; it++)
      bfr[it] = *(const s16x8*)&Xt[(w * 32 + it * 16 + l15) * 136 + ks * 32 + q4 * 8];
    #pragma unroll
    for (int ct = 0; ct < 4; ct++) {
      s16x8 afr = *(const s16x8*)&wb[(ct * 16 + l15) * 128 + ks * 32 + q4 * 8];
      #pragma unroll
      for (int it = 0; it < 2; it++) acc1[ct][it] = mfma16(afr, bfr[it], acc1[ct][it]);
    }
  }
  // bias + l2norm: lane holds c = ct*16+q4*4+r, i = it*16+l15 (+w*32)
  float qv[4][2][4];
  float ss[2] = {0.f, 0.f};
  #pragma unroll
  for (int ct = 0; ct < 4; ct++)
    #pragma unroll
    for (int it = 0; it < 2; it++)
      #pragma unroll
      for (int r = 0; r < 4; r++) {
        float v = acc1[ct][it][r] + bsh[ct * 16 + q4 * 4 + r];
        qv[ct][it][r] = v;
        ss[it] = fmaf(v, v, ss[it]);
      }
  #pragma unroll
  for (int it = 0; it < 2; it++) {
    ss[it] += __shfl_xor(ss[it], 16);
    ss[it] += __shfl_xor(ss[it], 32);
  }
  float scale[2];
  #pragma unroll
  for (int it = 0; it < 2; it++)
    scale[it] = (K_AMP * DN) / fmaxf(sqrtf(ss[it]), EPSN);
  __syncthreads();  // prior phase's Qt consumers are done before overwrite
  #pragma unroll
  for (int it = 0; it < 2; it++)
    #pragma unroll
    for (int ct = 0; ct < 4; ct++) {
      short4 pk;
      pk.x = f2bf(qv[ct][it][0] * scale[it]);
      pk.y = f2bf(qv[ct][it][1] * scale[it]);
      pk.z = f2bf(qv[ct][it][2] * scale[it]);
      pk.w = f2bf(qv[ct][it][3] * scale[it]);
      *(short4*)&Qt[(w * 32 + it * 16 + l15) * 72 + ct * 16 + q4 * 4] = pk;
    }
  __syncthreads();
  // GEMM2: QD[i=128][m=128] = Q' · P^T ; wave w: i in [w*32,+32) x all m
  #pragma unroll
  for (int mt = 0; mt < 8; mt++)
    #pragma unroll
    for (int it = 0; it < 2; it++) acc2[mt][it] = {0.f, 0.f, 0.f, 0.f};
  #pragma unroll
  for (int ks = 0; ks < 2; ks++) {
    s16x8 afr[2];
    #pragma unroll
    for (int it = 0; it < 2; it++)
      afr[it] = *(const s16x8*)&Qt[(w * 32 + it * 16 + l15) * 72 + ks * 32 + q4 * 8];
    #pragma unroll
    for (int mt = 0; mt < 8; mt++) {
      s16x8 bfr = *(const s16x8*)&pb[(mt * 16 + l15) * 64 + ks * 32 + q4 * 8];
      #pragma unroll
      for (int it = 0; it < 2; it++) acc2[mt][it] = mfma16(afr[it], bfr, acc2[mt][it]);
    }
  }
}

// Fused feature path: stage X once; Q phase -> qp; K phase -> e'=exp(kd-bm) bf16
// + per-block bmax, esum[m], xsum[c] partials. Global-max rescale deferred to k_g/k_ksum.
// LDS: Xt 34816 + (Qt|sred) 18432 + bsh 512 + wred 16 = 53776 B -> 3 blocks/CU.
__global__ __launch_bounds__(256) void k_qkf(
    const float* __restrict__ x,
    const short* __restrict__ w1b, const float* __restrict__ b1,
    const short* __restrict__ w2b, const float* __restrict__ b2,
    const short* __restrict__ pb,
    short* __restrict__ qp, short* __restrict__ ep,
    float* __restrict__ bmax, float* __restrict__ ksumb, float* __restrict__ xsumb) {
  const int n = blockIdx.y, i0 = blockIdx.x * 128;
  const int tid = threadIdx.x, lane = tid & 63, w = tid >> 6;
  const int l15 = lane & 15, q4 = lane >> 4;
  __shared__ __align__(16) short Xt[128 * 136];  // [i][c]
  __shared__ __align__(16) char smemQ[128 * 72 * 2];  // Qt [i][cr]; reused as sred[768] floats
  __shared__ float bsh[128];                     // b1 | b2
  __shared__ float wred[4];
  short* Qt = (short*)smemQ;
  float* sred = (float*)smemQ;   // [0..511] esum per (w,m); [512..767] xsum partials
  if (tid < 64) bsh[tid] = b1[tid];
  else if (tid < 128) bsh[tid] = b2[tid - 64];
  // stage Xt[i][c] bf16 (transpose: 4 c per thread-read, same i)
  #pragma unroll
  for (int u = 0; u < 16; u++) {
    int id = u * 256 + tid;
    int i = id & 127, cg = id >> 7;            // cg 0..31
    const float* xp = x + ((size_t)(n * CD + cg * 4) * HWD + i0 + i);
    short4 pk;
    pk.x = f2bf(xp[0]); pk.y = f2bf(xp[HWD]);
    pk.z = f2bf(xp[2 * HWD]); pk.w = f2bf(xp[3 * HWD]);
    *(short4*)&Xt[i * 136 + cg * 4] = pk;
  }
  __syncthreads();

  f32x4 acc2[8][2];

  // ===== Q phase =====
  qk_gemms(w1b, bsh, pb, Xt, Qt, tid, acc2);
  // D-tile: i = i0 + w*32 + it*16 + q4*4 + r ; m = mt*16 + l15
  #pragma unroll
  for (int it = 0; it < 2; it++)
    #pragma unroll
    for (int r = 0; r < 4; r++) {
      float mx = -3.0e38f;
      #pragma unroll
      for (int mt = 0; mt < 8; mt++) mx = fmaxf(mx, acc2[mt][it][r]);
      mx = fmaxf(mx, __shfl_xor(mx, 1));
      mx = fmaxf(mx, __shfl_xor(mx, 2));
      mx = fmaxf(mx, __shfl_xor(mx, 4));
      mx = fmaxf(mx, __shfl_xor(mx, 8));
      int i = i0 + w * 32 + it * 16 + q4 * 4 + r;
      #pragma unroll
      for (int mt = 0; mt < 8; mt++) {
        float e = RATIO * (__expf(acc2[mt][it][r] - DIAG - mx) + EPSK);
        qp[((size_t)n * HWD + i) * MF + mt * 16 + l15] = f2bf(e);
      }
    }

  // ===== K phase =====
  qk_gemms(w2b, bsh + 64, pb, Xt, Qt, tid, acc2);
  // block max
  float mxk = -3.0e38f;
  #pragma unroll
  for (int mt = 0; mt < 8; mt++)
    #pragma unroll
    for (int it = 0; it < 2; it++)
      #pragma unroll
      for (int r = 0; r < 4; r++) mxk = fmaxf(mxk, acc2[mt][it][r]);
  #pragma unroll
  for (int d = 1; d < 64; d <<= 1) mxk = fmaxf(mxk, __shfl_xor(mxk, d));
  if (lane == 0) wred[w] = mxk;
  __syncthreads();  // all waves past GEMM2 Qt reads -> sred may overwrite Qt
  const float bm = fmaxf(fmaxf(wred[0], wred[1]), fmaxf(wred[2], wred[3]));
  float es[8];
  #pragma unroll
  for (int mt = 0; mt < 8; mt++) es[mt] = 0.f;
  #pragma unroll
  for (int it = 0; it < 2; it++)
    #pragma unroll
    for (int r = 0; r < 4; r++) {
      int i = i0 + w * 32 + it * 16 + q4 * 4 + r;
      #pragma unroll
      for (int mt = 0; mt < 8; mt++) {
        float e = __expf(acc2[mt][it][r] - bm);   // e' in (0,1]; DIAG folded into sblk
        es[mt] += e;
        ep[((size_t)n * HWD + i) * MF + mt * 16 + l15] = f2bf(e);
      }
    }
  // reduce es over q4 (i-coverage of the wave); lanes with q4==0 hold per-(w,m) partials
  #pragma unroll
  for (int mt = 0; mt < 8; mt++) {
    es[mt] += __shfl_xor(es[mt], 16);
    es[mt] += __shfl_xor(es[mt], 32);
  }
  if (q4 == 0) {
    #pragma unroll
    for (int mt = 0; mt < 8; mt++) sred[w * 128 + mt * 16 + l15] = es[mt];
  }
  // xsum partial over staged Xt: thread -> (c = tid&127, half), 64 i each
  {
    int c = tid & 127, half = tid >> 7;
    float xs = 0.f;
    #pragma unroll 16
    for (int u = 0; u < 64; u++) xs += bf2f_s(Xt[(half * 64 + u) * 136 + c]);
    sred[512 + tid] = xs;
  }
  __syncthreads();
  const size_t pb0 = ((size_t)n * 128 + blockIdx.x) * 128;
  if (tid < 128) {
    ksumb[pb0 + tid] = sred[tid] + sred[128 + tid] + sred[256 + tid] + sred[384 + tid];
  } else {
    int c = tid - 128;
    xsumb[pb0 + c] = sred[512 + c] + sred[640 + c];
  }
  if (tid == 0) bmax[n * 128 + blockIdx.x] = bm;
}

// Merged: global key max (redundant per block) + sblk + ksum + xsum.
// sblk_b = RATIO * exp(bmax_b - gm - DIAG);
// ksum[n][m] = sum_b sblk_b * esum_b[m] + ratio*eps*HW ; xsum[n][c] = sum_b xsum_b[c]
__global__ void k_ksum(const float* __restrict__ bmax, const float* __restrict__ ksumb,
                       const float* __restrict__ xsumb, float* __restrict__ sblk,
                       float* __restrict__ ksum, float* __restrict__ xsum) {
  __shared__ float red[256];
  __shared__ float sb_sh[256];
  int t = threadIdx.x;
  float v = -3.0e38f;
  #pragma unroll
  for (int u = 0; u < 8; u++) v = fmaxf(v, bmax[t + 256 * u]);
  red[t] = v;
  __syncthreads();
  for (int s = 128; s > 0; s >>= 1) {
    if (t < s) red[t] = fmaxf(red[t], red[t + s]);
    __syncthreads();
  }
  const float gm = red[0];
  int g = blockIdx.x * 256 + t;   // 0..2047 ; block covers 2 consecutive n
  int n = g >> 7, m = g & 127;
  float sv = RATIO * __expf(bmax[g] - gm - DIAG);
  sb_sh[t] = sv;
  sblk[g] = sv;
  __syncthreads();
  const float* kb = ksumb + ((size_t)n << 14) + m;
  const float* xb = xsumb + ((size_t)n << 14) + m;
  const float* sb = &sb_sh[(t >> 7) * 128];
  float s = 0.f, xs = 0.f;
  #pragma unroll 4
  for (int b = 0; b < 128; b++) {
    s = fmaf(sb[b], kb[(size_t)b * 128], s);
    xs += xb[(size_t)b * 128];
  }
  ksum[g] = s + RATIO * EPSK * 16384.0f;
  xsum[g] = xs;
}

// G partials: Gp[slab][n][m][c] = sum_{i in slab} e'[i][m] * (sblk*x)[c][i]  (K=512/block)
__global__ __launch_bounds__(256) void k_g(const float* __restrict__ x,
                                           const short* __restrict__ ep,
                                           const float* __restrict__ sblk,
                                           float* __restrict__ gp) {
  const int slab = blockIdx.x, n = blockIdx.y;
  const int t = threadIdx.x, lane = t & 63, w = t >> 6;
  const int l15 = lane & 15, q4 = lane >> 4;
  __shared__ short kl[64 * 136];   // [i][m]  (e' bf16)
  __shared__ short xl[128 * 72];   // [c][i]  (pre-scaled by sblk)
  f32x4 acc[2][8];
  #pragma unroll
  for (int mt = 0; mt < 2; mt++)
    #pragma unroll
    for (int ct = 0; ct < 8; ct++) acc[mt][ct] = {0.f, 0.f, 0.f, 0.f};
  for (int ch = 0; ch < 8; ch++) {
    int ib = slab * 512 + ch * 64;
    const float sf = sblk[n * 128 + slab * 4 + (ch >> 1)];  // uniform per 64-i chunk
    __syncthreads();
    #pragma unroll
    for (int u = 0; u < 4; u++) {                   // e' chunk [64 i][128 m]
      int id = u * 256 + t, ii = id >> 4, m8 = (id & 15) * 8;
      *(s16x8*)&kl[ii * 136 + m8] =
          *(const s16x8*)&ep[((size_t)n * HWD + ib + ii) * MF + m8];
    }
    #pragma unroll
    for (int u = 0; u < 8; u++) {                   // x chunk [128 c][64 i], scaled
      int id = u * 256 + t, c = id >> 4, i4 = (id & 15) * 4;
      const float4 v = *(const float4*)(x + ((size_t)n * CD + c) * HWD + ib + i4);
      short4 pk;
      pk.x = f2bf(v.x * sf); pk.y = f2bf(v.y * sf);
      pk.z = f2bf(v.z * sf); pk.w = f2bf(v.w * sf);
      *(short4*)&xl[c * 72 + i4] = pk;
    }
    __syncthreads();
    #pragma unroll
    for (int ks = 0; ks < 2; ks++) {
      s16x8 afr[2];
      #pragma unroll
      for (int mt = 0; mt < 2; mt++) {              // transpose-read e': A[m][k=i]
        int m = w * 32 + mt * 16 + l15;
        short tmp[8];
        #pragma unroll
        for (int j = 0; j < 8; j++) tmp[j] = kl[(ks * 32 + q4 * 8 + j) * 136 + m];
        afr[mt] = *(s16x8*)tmp;
      }
      #pragma unroll
      for (int ct = 0; ct < 8; ct++) {
        s16x8 bfr = *(const s16x8*)&xl[(ct * 16 + l15) * 72 + ks * 32 + q4 * 8];
        #pragma unroll
        for (int mt = 0; mt < 2; mt++) acc[mt][ct] = mfma16(afr[mt], bfr, acc[mt][ct]);
      }
    }
  }
  float* g = gp + (((size_t)slab * NB + n) << 14);
  #pragma unroll
  for (int mt = 0; mt < 2; mt++)
    #pragma unroll
    for (int ct = 0; ct < 8; ct++)
      #pragma unroll
      for (int r = 0; r < 4; r++)
        g[(w * 32 + mt * 16 + q4 * 4 + r) * CD + ct * 16 + l15] = acc[mt][ct][r];
}

__global__ void k_gred(const float* __restrict__ gp, const float* __restrict__ xsum,
                       float* __restrict__ G) {
  int t = blockIdx.x * 256 + threadIdx.x;   // 262144
  int n = t >> 14, r = t & 16383;
  float s = 0.f;
  #pragma unroll
  for (int sc = 0; sc < 32; sc++) s += gp[(((size_t)sc * NB + n) << 14) + r];
  G[((size_t)n << 14) + r] = s + (RATIO * EPSK) * xsum[n * 128 + (r & 127)];
}

// ctx[m][c] = sum_c2 wa[c][c2]*G[m][c2] + ba[c]*ksum[m]; writes ctx^T bf16 [c][m]
__global__ __launch_bounds__(256) void k_ctx(const float* __restrict__ G,
                                             const float* __restrict__ wa,
                                             const float* __restrict__ ba,
                                             const float* __restrict__ ksum,
                                             short* __restrict__ ctxb) {
  int n = blockIdx.x;
  int tm = threadIdx.x & 15, tc = threadIdx.x >> 4;
  const float* Gn = G + ((size_t)n << 14);
  float acc[8][8];
  #pragma unroll
  for (int a = 0; a < 8; a++)
    #pragma unroll
    for (int b = 0; b < 8; b++) acc[a][b] = 0.f;
  for (int c2 = 0; c2 < CD; c2 += 4) {
    float4 g4[8], w4[8];
    #pragma unroll
    for (int a = 0; a < 8; a++) g4[a] = *(const float4*)&Gn[(tm * 8 + a) * CD + c2];
    #pragma unroll
    for (int b = 0; b < 8; b++) w4[b] = *(const float4*)&wa[(tc * 8 + b) * CD + c2];
    #pragma unroll
    for (int a = 0; a < 8; a++)
      #pragma unroll
      for (int b = 0; b < 8; b++) {
        acc[a][b] = fmaf(g4[a].x, w4[b].x, acc[a][b]);
        acc[a][b] = fmaf(g4[a].y, w4[b].y, acc[a][b]);
        acc[a][b] = fmaf(g4[a].z, w4[b].z, acc[a][b]);
        acc[a][b] = fmaf(g4[a].w, w4[b].w, acc[a][b]);
      }
  }
  #pragma unroll
  for (int a = 0; a < 8; a++) {
    int m = tm * 8 + a;
    float km = ksum[n * MF + m];
    #pragma unroll
    for (int b = 0; b < 8; b++) {
      int c = tc * 8 + b;
      ctxb[((size_t)n * CD + c) * MF + m] = f2bf(acc[a][b] + ba[c] * km);
    }
  }
}

// out[c][i] = dinv[i] * sum_m ctx^T[c][m] * qp[i][m] ; dinv = RES / (qp·ksum)
__global__ __launch_bounds__(256) void k_out(const short* __restrict__ qp,
                                             const short* __restrict__ ctxb,
                                             const float* __restrict__ ksum,
                                             float* __restrict__ out) {
  const int n = blockIdx.y, i0 = blockIdx.x * 128;
  const int t = threadIdx.x, lane = t & 63, w = t >> 6;
  const int l15 = lane & 15, q4 = lane >> 4;
  __shared__ short qt[128 * 136];  // [i][m]
  __shared__ float ksl[128];
  __shared__ float dinv[128];
  if (t < 128) ksl[t] = ksum[n * MF + t];
  #pragma unroll
  for (int u = 0; u < 8; u++) {
    int id = u * 256 + t, i = id >> 4, m8 = (id & 15) * 8;
    *(s16x8*)&qt[i * 136 + m8] =
        *(const s16x8*)&qp[((size_t)n * HWD + i0 + i) * MF + m8];
  }
  __syncthreads();
  if (t < 128) {
    float s = 0.f;
    #pragma unroll
    for (int mb = 0; mb < 16; mb++) {
      s16x8 v = *(const s16x8*)&qt[t * 136 + mb * 8];
      #pragma unroll
      for (int j = 0; j < 8; j++) s = fmaf(bf2f_s(v[j]), ksl[mb * 8 + j], s);
    }
    dinv[t] = RES / s;
  }
  f32x4 acc[8][2];
  #pragma unroll
  for (int it = 0; it < 8; it++)
    #pragma unroll
    for (int ct = 0; ct < 2; ct++) acc[it][ct] = {0.f, 0.f, 0.f, 0.f};
  #pragma unroll
  for (int ks = 0; ks < 4; ks++) {
    s16x8 afr[2];
    #pragma unroll
    for (int ct = 0; ct < 2; ct++)
      afr[ct] = *(const s16x8*)&ctxb[((size_t)n * CD + w * 32 + ct * 16 + l15) * MF +
                                     ks * 32 + q4 * 8];
    #pragma unroll
    for (int it = 0; it < 8; it++) {
      s16x8 bfr = *(const s16x8*)&qt[(it * 16 + l15) * 136 + ks * 32 + q4 * 8];
      #pragma unroll
      for (int ct = 0; ct < 2; ct++) acc[it][ct] = mfma16(afr[ct], bfr, acc[it][ct]);
    }
  }
  __syncthreads();  // dinv ready
  #pragma unroll
  for (int it = 0; it < 8; it++) {
    float dv = dinv[it * 16 + l15];
    #pragma unroll
    for (int ct = 0; ct < 2; ct++)
      #pragma unroll
      for (int r = 0; r < 4; r++)
        out[((size_t)n * CD + w * 32 + ct * 16 + q4 * 4 + r) * HWD + i0 + it * 16 + l15] =
            acc[it][ct][r] * dv;
  }
}

extern "C" void kernel_launch(void* const* d_in, const int* in_sizes, int n_in,
                              void* d_out, int out_size, void* d_ws, size_t ws_size,
                              hipStream_t stream) {
  (void)in_sizes; (void)n_in; (void)out_size;
  const float* x    = (const float*)d_in[0];
  const float* w1   = (const float*)d_in[1];
  const float* b1   = (const float*)d_in[2];
  const float* w2   = (const float*)d_in[3];
  const float* b2   = (const float*)d_in[4];
  const float* wa   = (const float*)d_in[5];
  const float* ba   = (const float*)d_in[6];
  const float* proj = (const float*)d_in[7];
  float* ws  = (float*)d_ws;
  float* out = (float*)d_out;

  if (ws_size < WS_FLOATS * sizeof(float)) {
    fprintf(stderr, "ENLCA: workspace too small: need %zu, have %zu\n",
            WS_FLOATS * sizeof(float), ws_size);
  }

  short* qpB   = (short*)(ws + OFF_QP);
  short* epB   = (short*)(ws + OFF_EP);
  float* gpF   = ws + OFF_GP;
  float* GF    = ws + OFF_G;
  short* ctxB  = (short*)(ws + OFF_CTXB);
  float* ksumF = ws + OFF_KSUM;
  float* xsumF = ws + OFF_XSUM;
  float* ksumbF= ws + OFF_KSUMB;
  float* xsumbF= ws + OFF_XSUMB;
  float* bmaxF = ws + OFF_BMAX;
  float* sblkF = ws + OFF_SBLK;
  short* w1B   = (short*)(ws + OFF_W1B);
  short* w2B   = (short*)(ws + OFF_W2B);
  short* pB    = (short*)(ws + OFF_PB);

  k_prep<<<32, 256, 0, stream>>>(w1, w2, proj, w1B, w2B, pB);
  k_qkf<<<dim3(128, 16), 256, 0, stream>>>(x, w1B, b1, w2B, b2, pB,
                                           qpB, epB, bmaxF, ksumbF, xsumbF);
  k_ksum<<<8, 256, 0, stream>>>(bmaxF, ksumbF, xsumbF, sblkF, ksumF, xsumF);
  k_g<<<dim3(32, 16), 256, 0, stream>>>(x, epB, sblkF, gpF);
  k_gred<<<1024, 256, 0, stream>>>(gpF, xsumF, GF);
  k_ctx<<<16, 256, 0, stream>>>(GF, wa, ba, ksumF, ctxB);
  k_out<<<dim3(128, 16), 256, 0, stream>>>(qpB, ctxB, ksumF, out);
}

// Round 9
// 443.074 us; speedup vs baseline: 1.0695x; 1.0536x over previous
//
#include <hip/hip_runtime.h>
#include <hip/hip_bf16.h>
#include <cstdio>
#include <cstdint>

// N=16, C=128, HW=16384, Cr=64, M=128
#define HWD 16384
#define NB  16
#define CD  128
#define CR  64
#define MF  128

constexpr float K_AMP = 2.4494897427831781f;   // sqrt(6)
constexpr float DN    = 0.35355339059327379f;  // 64^-0.25
constexpr float RATIO = 0.088388347648318447f; // 128^-0.5
constexpr float EPSN  = 5e-5f;
constexpr float EPSK  = 1e-4f;
constexpr float RES   = 0.1f;
constexpr float DIAG  = 0.375f;  // ||k||^2=6 after l2norm => kdiag = 0.5*6*dn^2 exactly

typedef __attribute__((ext_vector_type(4))) float f32x4;
typedef __attribute__((ext_vector_type(8))) short s16x8;

__device__ __forceinline__ short f2bf(float f) {
  __hip_bfloat16 h = __float2bfloat16(f);
  short s; __builtin_memcpy(&s, &h, 2); return s;
}
__device__ __forceinline__ float bf2f_s(short s) {
  __hip_bfloat16 h; __builtin_memcpy(&h, &s, 2); return __bfloat162float(h);
}
__device__ __forceinline__ f32x4 mfma16(s16x8 a, s16x8 b, f32x4 c) {
  return __builtin_amdgcn_mfma_f32_16x16x32_bf16(a, b, c, 0, 0, 0);
}

// ---- workspace layout (float offsets) ----
constexpr size_t OFF_QP   = 0;                          // bf16 [N][HW][M]
constexpr size_t OFF_EP   = OFF_QP   + 16777216;        // bf16 e' [N][HW][M]
constexpr size_t OFF_GP   = OFF_EP   + 16777216;        // fp32 [32][N][M][C]
constexpr size_t OFF_G    = OFF_GP   + 8388608;         // fp32 [N][M][C]
constexpr size_t OFF_CTXB = OFF_G    + 262144;          // bf16 [N][C][M]
constexpr size_t OFF_KSUM = OFF_CTXB + 131072;          // fp32 [N][M]
constexpr size_t OFF_XSUM = OFF_KSUM + 2048;            // fp32 [N][C]
constexpr size_t OFF_KSUMB= OFF_XSUM + 2048;            // fp32 [N][128][M]
constexpr size_t OFF_XSUMB= OFF_KSUMB+ 262144;          // fp32 [N][128][C]
constexpr size_t OFF_BMAX = OFF_XSUMB+ 262144;          // fp32 [N][128]
constexpr size_t OFF_SBLK = OFF_BMAX + 2048;            // fp32 [N][128]
constexpr size_t OFF_W1B  = OFF_SBLK + 2048;            // bf16 [64][128]
constexpr size_t OFF_W2B  = OFF_W1B  + 4096;
constexpr size_t OFF_PB   = OFF_W2B  + 4096;            // bf16 [128][64]
constexpr size_t WS_FLOATS = OFF_PB  + 4096;

// ---- weights -> bf16 ----
__global__ void k_prep(const float* __restrict__ w1, const float* __restrict__ w2,
                       const float* __restrict__ proj,
                       short* __restrict__ w1b, short* __restrict__ w2b, short* __restrict__ pb) {
  int t = blockIdx.x * 256 + threadIdx.x;   // 8192 threads; all three are 8192 elems
  w1b[t] = f2bf(w1[t]);
  w2b[t] = f2bf(w2[t]);
  pb[t]  = f2bf(proj[t]);
}

// GEMM1 (W·X + bias + l2norm -> Qt) then GEMM2 (Qt·P^T -> acc2). Shared by Q and K phases.
// NOTE: barriers around the Qt write are kept deliberately — removing them let the
// compiler inflate VGPR 108->132 and cost 16 us (round-3 regression). Qt pitch is 64
// (no pad): ~16-way conflict on 4 reads/thread, ~1% — accepted to fit 3 blocks/CU LDS.
__device__ __forceinline__ void qk_gemms(const short* __restrict__ wb,
                                         const float* __restrict__ bsh,
                                         const short* __restrict__ pb,
                                         const short* Xt, short* Qt,
                                         int tid, f32x4 (&acc2)[8][2]) {
  const int lane = tid & 63, w = tid >> 6;
  const int l15 = lane & 15, q4 = lane >> 4;
  f32x4 acc1[4][2];
  #pragma unroll
  for (int ct = 0; ct < 4; ct++)
    #pragma unroll
    for (int it = 0; it < 2; it++) acc1[ct][it] = {0.f, 0.f, 0.f, 0.f};
  #pragma unroll
  for (int ks = 0; ks < 4; ks++) {
    s16x8 bfr[2];
    #pragma unroll
    for (int it = 0; it < 2; it++)
      bfr[it] = *(const s16x8*)&Xt[(w * 32 + it * 16 + l15) * 136 + ks * 32 + q4 * 8];
    #pragma unroll
    for (int ct = 0; ct < 4; ct++) {
      s16x8 afr = *(const s16x8*)&wb[(ct * 16 + l15) * 128 + ks * 32 + q4 * 8];
      #pragma unroll
      for (int it = 0; it < 2; it++) acc1[ct][it] = mfma16(afr, bfr[it], acc1[ct][it]);
    }
  }
  // bias + l2norm: lane holds c = ct*16+q4*4+r, i = it*16+l15 (+w*32)
  float qv[4][2][4];
  float ss[2] = {0.f, 0.f};
  #pragma unroll
  for (int ct = 0; ct < 4; ct++)
    #pragma unroll
    for (int it = 0; it < 2; it++)
      #pragma unroll
      for (int r = 0; r < 4; r++) {
        float v = acc1[ct][it][r] + bsh[ct * 16 + q4 * 4 + r];
        qv[ct][it][r] = v;
        ss[it] = fmaf(v, v, ss[it]);
      }
  #pragma unroll
  for (int it = 0; it < 2; it++) {
    ss[it] += __shfl_xor(ss[it], 16);
    ss[it] += __shfl_xor(ss[it], 32);
  }
  float scale[2];
  #pragma unroll
  for (int it = 0; it < 2; it++)
    scale[it] = (K_AMP * DN) / fmaxf(sqrtf(ss[it]), EPSN);
  __syncthreads();  // prior phase's Qt consumers are done before overwrite
  #pragma unroll
  for (int it = 0; it < 2; it++)
    #pragma unroll
    for (int ct = 0; ct < 4; ct++) {
      short4 pk;
      pk.x = f2bf(qv[ct][it][0] * scale[it]);
      pk.y = f2bf(qv[ct][it][1] * scale[it]);
      pk.z = f2bf(qv[ct][it][2] * scale[it]);
      pk.w = f2bf(qv[ct][it][3] * scale[it]);
      *(short4*)&Qt[(w * 32 + it * 16 + l15) * 64 + ct * 16 + q4 * 4] = pk;
    }
  __syncthreads();
  // GEMM2: QD[i=128][m=128] = Q' · P^T ; wave w: i in [w*32,+32) x all m
  #pragma unroll
  for (int mt = 0; mt < 8; mt++)
    #pragma unroll
    for (int it = 0; it < 2; it++) acc2[mt][it] = {0.f, 0.f, 0.f, 0.f};
  #pragma unroll
  for (int ks = 0; ks < 2; ks++) {
    s16x8 afr[2];
    #pragma unroll
    for (int it = 0; it < 2; it++)
      afr[it] = *(const s16x8*)&Qt[(w * 32 + it * 16 + l15) * 64 + ks * 32 + q4 * 8];
    #pragma unroll
    for (int mt = 0; mt < 8; mt++) {
      s16x8 bfr = *(const s16x8*)&pb[(mt * 16 + l15) * 64 + ks * 32 + q4 * 8];
      #pragma unroll
      for (int it = 0; it < 2; it++) acc2[mt][it] = mfma16(afr[it], bfr, acc2[mt][it]);
    }
  }
}

// Fused feature path: stage X once; Q phase -> qp; K phase -> e'=exp(kd-bm) bf16
// + per-block bmax, esum[m], xsum[c] partials (LDS float atomics).
// LDS: Xt 34816 + Qt 16384 + bsh 512 + wred 16 + esum 512 + xsred 512 = 52752 B
// -> target 3 blocks/CU (round-8 showed 54272 still gave 2; this is the safe margin test).
__global__ __launch_bounds__(256) void k_qkf(
    const float* __restrict__ x,
    const short* __restrict__ w1b, const float* __restrict__ b1,
    const short* __restrict__ w2b, const float* __restrict__ b2,
    const short* __restrict__ pb,
    short* __restrict__ qp, short* __restrict__ ep,
    float* __restrict__ bmax, float* __restrict__ ksumb, float* __restrict__ xsumb) {
  const int n = blockIdx.y, i0 = blockIdx.x * 128;
  const int tid = threadIdx.x, lane = tid & 63, w = tid >> 6;
  const int l15 = lane & 15, q4 = lane >> 4;
  __shared__ __align__(16) short Xt[128 * 136];  // [i][c]
  __shared__ __align__(16) short Qt[128 * 64];   // [i][cr]
  __shared__ float bsh[128];                     // b1 | b2
  __shared__ float wred[4];
  __shared__ float esum[128];                    // K-phase per-m block sums (atomic)
  __shared__ float xsred[128];                   // per-c x sums (atomic)
  if (tid < 64) bsh[tid] = b1[tid];
  else if (tid < 128) bsh[tid] = b2[tid - 64];
  if (tid < 128) { esum[tid] = 0.f; xsred[tid] = 0.f; }
  // stage Xt[i][c] bf16 (transpose: 4 c per thread-read, same i)
  #pragma unroll
  for (int u = 0; u < 16; u++) {
    int id = u * 256 + tid;
    int i = id & 127, cg = id >> 7;            // cg 0..31
    const float* xp = x + ((size_t)(n * CD + cg * 4) * HWD + i0 + i);
    short4 pk;
    pk.x = f2bf(xp[0]); pk.y = f2bf(xp[HWD]);
    pk.z = f2bf(xp[2 * HWD]); pk.w = f2bf(xp[3 * HWD]);
    *(short4*)&Xt[i * 136 + cg * 4] = pk;
  }
  __syncthreads();

  f32x4 acc2[8][2];

  // ===== Q phase =====
  qk_gemms(w1b, bsh, pb, Xt, Qt, tid, acc2);
  // D-tile: i = i0 + w*32 + it*16 + q4*4 + r ; m = mt*16 + l15
  #pragma unroll
  for (int it = 0; it < 2; it++)
    #pragma unroll
    for (int r = 0; r < 4; r++) {
      float mx = -3.0e38f;
      #pragma unroll
      for (int mt = 0; mt < 8; mt++) mx = fmaxf(mx, acc2[mt][it][r]);
      mx = fmaxf(mx, __shfl_xor(mx, 1));
      mx = fmaxf(mx, __shfl_xor(mx, 2));
      mx = fmaxf(mx, __shfl_xor(mx, 4));
      mx = fmaxf(mx, __shfl_xor(mx, 8));
      int i = i0 + w * 32 + it * 16 + q4 * 4 + r;
      #pragma unroll
      for (int mt = 0; mt < 8; mt++) {
        float e = RATIO * (__expf(acc2[mt][it][r] - DIAG - mx) + EPSK);
        qp[((size_t)n * HWD + i) * MF + mt * 16 + l15] = f2bf(e);
      }
    }

  // ===== K phase =====
  qk_gemms(w2b, bsh + 64, pb, Xt, Qt, tid, acc2);
  // block max
  float mxk = -3.0e38f;
  #pragma unroll
  for (int mt = 0; mt < 8; mt++)
    #pragma unroll
    for (int it = 0; it < 2; it++)
      #pragma unroll
      for (int r = 0; r < 4; r++) mxk = fmaxf(mxk, acc2[mt][it][r]);
  #pragma unroll
  for (int d = 1; d < 64; d <<= 1) mxk = fmaxf(mxk, __shfl_xor(mxk, d));
  if (lane == 0) wred[w] = mxk;
  __syncthreads();
  const float bm = fmaxf(fmaxf(wred[0], wred[1]), fmaxf(wred[2], wred[3]));
  float es[8];
  #pragma unroll
  for (int mt = 0; mt < 8; mt++) es[mt] = 0.f;
  #pragma unroll
  for (int it = 0; it < 2; it++)
    #pragma unroll
    for (int r = 0; r < 4; r++) {
      int i = i0 + w * 32 + it * 16 + q4 * 4 + r;
      #pragma unroll
      for (int mt = 0; mt < 8; mt++) {
        float e = __expf(acc2[mt][it][r] - bm);   // e' in (0,1]; DIAG folded into sblk
        es[mt] += e;
        ep[((size_t)n * HWD + i) * MF + mt * 16 + l15] = f2bf(e);
      }
    }
  // reduce es over q4, then per-block sum via LDS atomics (4-way contention max)
  #pragma unroll
  for (int mt = 0; mt < 8; mt++) {
    es[mt] += __shfl_xor(es[mt], 16);
    es[mt] += __shfl_xor(es[mt], 32);
  }
  if (q4 == 0) {
    #pragma unroll
    for (int mt = 0; mt < 8; mt++) atomicAdd(&esum[mt * 16 + l15], es[mt]);
  }
  // xsum partial over staged Xt: thread -> (c = tid&127, half), 64 i each, atomic join
  {
    int c = tid & 127, half = tid >> 7;
    float xs = 0.f;
    #pragma unroll 16
    for (int u = 0; u < 64; u++) xs += bf2f_s(Xt[(half * 64 + u) * 136 + c]);
    atomicAdd(&xsred[c], xs);
  }
  __syncthreads();
  const size_t pb0 = ((size_t)n * 128 + blockIdx.x) * 128;
  if (tid < 128) {
    ksumb[pb0 + tid] = esum[tid];
  } else {
    int c = tid - 128;
    xsumb[pb0 + c] = xsred[c];
  }
  if (tid == 0) bmax[n * 128 + blockIdx.x] = bm;
}

// Merged: global key max (redundant per block) + sblk + ksum + xsum.
// sblk_b = RATIO * exp(bmax_b - gm - DIAG);
// ksum[n][m] = sum_b sblk_b * esum_b[m] + ratio*eps*HW ; xsum[n][c] = sum_b xsum_b[c]
__global__ void k_ksum(const float* __restrict__ bmax, const float* __restrict__ ksumb,
                       const float* __restrict__ xsumb, float* __restrict__ sblk,
                       float* __restrict__ ksum, float* __restrict__ xsum) {
  __shared__ float red[256];
  __shared__ float sb_sh[256];
  int t = threadIdx.x;
  float v = -3.0e38f;
  #pragma unroll
  for (int u = 0; u < 8; u++) v = fmaxf(v, bmax[t + 256 * u]);
  red[t] = v;
  __syncthreads();
  for (int s = 128; s > 0; s >>= 1) {
    if (t < s) red[t] = fmaxf(red[t], red[t + s]);
    __syncthreads();
  }
  const float gm = red[0];
  int g = blockIdx.x * 256 + t;   // 0..2047 ; block covers 2 consecutive n
  int n = g >> 7, m = g & 127;
  float sv = RATIO * __expf(bmax[g] - gm - DIAG);
  sb_sh[t] = sv;
  sblk[g] = sv;
  __syncthreads();
  const float* kb = ksumb + ((size_t)n << 14) + m;
  const float* xb = xsumb + ((size_t)n << 14) + m;
  const float* sb = &sb_sh[(t >> 7) * 128];
  float s = 0.f, xs = 0.f;
  #pragma unroll 4
  for (int b = 0; b < 128; b++) {
    s = fmaf(sb[b], kb[(size_t)b * 128], s);
    xs += xb[(size_t)b * 128];
  }
  ksum[g] = s + RATIO * EPSK * 16384.0f;
  xsum[g] = xs;
}

// G partials: Gp[slab][n][m][c] = sum_{i in slab} e'[i][m] * (sblk*x)[c][i]  (K=512/block)
__global__ __launch_bounds__(256) void k_g(const float* __restrict__ x,
                                           const short* __restrict__ ep,
                                           const float* __restrict__ sblk,
                                           float* __restrict__ gp) {
  const int slab = blockIdx.x, n = blockIdx.y;
  const int t = threadIdx.x, lane = t & 63, w = t >> 6;
  const int l15 = lane & 15, q4 = lane >> 4;
  __shared__ short kl[64 * 136];   // [i][m]  (e' bf16)
  __shared__ short xl[128 * 72];   // [c][i]  (pre-scaled by sblk)
  f32x4 acc[2][8];
  #pragma unroll
  for (int mt = 0; mt < 2; mt++)
    #pragma unroll
    for (int ct = 0; ct < 8; ct++) acc[mt][ct] = {0.f, 0.f, 0.f, 0.f};
  for (int ch = 0; ch < 8; ch++) {
    int ib = slab * 512 + ch * 64;
    const float sf = sblk[n * 128 + slab * 4 + (ch >> 1)];  // uniform per 64-i chunk
    __syncthreads();
    #pragma unroll
    for (int u = 0; u < 4; u++) {                   // e' chunk [64 i][128 m]
      int id = u * 256 + t, ii = id >> 4, m8 = (id & 15) * 8;
      *(s16x8*)&kl[ii * 136 + m8] =
          *(const s16x8*)&ep[((size_t)n * HWD + ib + ii) * MF + m8];
    }
    #pragma unroll
    for (int u = 0; u < 8; u++) {                   // x chunk [128 c][64 i], scaled
      int id = u * 256 + t, c = id >> 4, i4 = (id & 15) * 4;
      const float4 v = *(const float4*)(x + ((size_t)n * CD + c) * HWD + ib + i4);
      short4 pk;
      pk.x = f2bf(v.x * sf); pk.y = f2bf(v.y * sf);
      pk.z = f2bf(v.z * sf); pk.w = f2bf(v.w * sf);
      *(short4*)&xl[c * 72 + i4] = pk;
    }
    __syncthreads();
    #pragma unroll
    for (int ks = 0; ks < 2; ks++) {
      s16x8 afr[2];
      #pragma unroll
      for (int mt = 0; mt < 2; mt++) {              // transpose-read e': A[m][k=i]
        int m = w * 32 + mt * 16 + l15;
        short tmp[8];
        #pragma unroll
        for (int j = 0; j < 8; j++) tmp[j] = kl[(ks * 32 + q4 * 8 + j) * 136 + m];
        afr[mt] = *(s16x8*)tmp;
      }
      #pragma unroll
      for (int ct = 0; ct < 8; ct++) {
        s16x8 bfr = *(const s16x8*)&xl[(ct * 16 + l15) * 72 + ks * 32 + q4 * 8];
        #pragma unroll
        for (int mt = 0; mt < 2; mt++) acc[mt][ct] = mfma16(afr[mt], bfr, acc[mt][ct]);
      }
    }
  }
  float* g = gp + (((size_t)slab * NB + n) << 14);
  #pragma unroll
  for (int mt = 0; mt < 2; mt++)
    #pragma unroll
    for (int ct = 0; ct < 8; ct++)
      #pragma unroll
      for (int r = 0; r < 4; r++)
        g[(w * 32 + mt * 16 + q4 * 4 + r) * CD + ct * 16 + l15] = acc[mt][ct][r];
}

__global__ void k_gred(const float* __restrict__ gp, const float* __restrict__ xsum,
                       float* __restrict__ G) {
  int t = blockIdx.x * 256 + threadIdx.x;   // 262144
  int n = t >> 14, r = t & 16383;
  float s = 0.f;
  #pragma unroll
  for (int sc = 0; sc < 32; sc++) s += gp[(((size_t)sc * NB + n) << 14) + r];
  G[((size_t)n << 14) + r] = s + (RATIO * EPSK) * xsum[n * 128 + (r & 127)];
}

// ctx[m][c] = sum_c2 wa[c][c2]*G[m][c2] + ba[c]*ksum[m]; writes ctx^T bf16 [c][m]
// Parallelized: 128 blocks (16 n x 8 m-tiles of 16) instead of 16 — was 94% GPU-idle.
__global__ __launch_bounds__(256) void k_ctx(const float* __restrict__ G,
                                             const float* __restrict__ wa,
                                             const float* __restrict__ ba,
                                             const float* __restrict__ ksum,
                                             short* __restrict__ ctxb) {
  int n = blockIdx.x >> 3;
  int m = (blockIdx.x & 7) * 16 + (threadIdx.x & 15);
  int tc = threadIdx.x >> 4;            // 16 c-groups of 8
  const float* Gn = G + ((size_t)n << 14);
  float acc[8];
  #pragma unroll
  for (int b = 0; b < 8; b++) acc[b] = 0.f;
  for (int c2 = 0; c2 < CD; c2 += 4) {
    float4 g4 = *(const float4*)&Gn[m * CD + c2];
    #pragma unroll
    for (int b = 0; b < 8; b++) {
      float4 w4 = *(const float4*)&wa[(tc * 8 + b) * CD + c2];
      acc[b] = fmaf(g4.x, w4.x, acc[b]);
      acc[b] = fmaf(g4.y, w4.y, acc[b]);
      acc[b] = fmaf(g4.z, w4.z, acc[b]);
      acc[b] = fmaf(g4.w, w4.w, acc[b]);
    }
  }
  float km = ksum[n * MF + m];
  #pragma unroll
  for (int b = 0; b < 8; b++) {
    int c = tc * 8 + b;
    ctxb[((size_t)n * CD + c) * MF + m] = f2bf(acc[b] + ba[c] * km);
  }
}

// out[c][i] = dinv[i] * sum_m ctx^T[c][m] * qp[i][m] ; dinv = RES / (qp·ksum)
__global__ __launch_bounds__(256) void k_out(const short* __restrict__ qp,
                                             const short* __restrict__ ctxb,
                                             const float* __restrict__ ksum,
                                             float* __restrict__ out) {
  const int n = blockIdx.y, i0 = blockIdx.x * 128;
  const int t = threadIdx.x, lane = t & 63, w = t >> 6;
  const int l15 = lane & 15, q4 = lane >> 4;
  __shared__ short qt[128 * 136];  // [i][m]
  __shared__ float ksl[128];
  __shared__ float dinv[128];
  if (t < 128) ksl[t] = ksum[n * MF + t];
  #pragma unroll
  for (int u = 0; u < 8; u++) {
    int id = u * 256 + t, i = id >> 4, m8 = (id & 15) * 8;
    *(s16x8*)&qt[i * 136 + m8] =
        *(const s16x8*)&qp[((size_t)n * HWD + i0 + i) * MF + m8];
  }
  __syncthreads();
  if (t < 128) {
    float s = 0.f;
    #pragma unroll
    for (int mb = 0; mb < 16; mb++) {
      s16x8 v = *(const s16x8*)&qt[t * 136 + mb * 8];
      #pragma unroll
      for (int j = 0; j < 8; j++) s = fmaf(bf2f_s(v[j]), ksl[mb * 8 + j], s);
    }
    dinv[t] = RES / s;
  }
  f32x4 acc[8][2];
  #pragma unroll
  for (int it = 0; it < 8; it++)
    #pragma unroll
    for (int ct = 0; ct < 2; ct++) acc[it][ct] = {0.f, 0.f, 0.f, 0.f};
  #pragma unroll
  for (int ks = 0; ks < 4; ks++) {
    s16x8 afr[2];
    #pragma unroll
    for (int ct = 0; ct < 2; ct++)
      afr[ct] = *(const s16x8*)&ctxb[((size_t)n * CD + w * 32 + ct * 16 + l15) * MF +
                                     ks * 32 + q4 * 8];
    #pragma unroll
    for (int it = 0; it < 8; it++) {
      s16x8 bfr = *(const s16x8*)&qt[(it * 16 + l15) * 136 + ks * 32 + q4 * 8];
      #pragma unroll
      for (int ct = 0; ct < 2; ct++) acc[it][ct] = mfma16(afr[ct], bfr, acc[it][ct]);
    }
  }
  __syncthreads();  // dinv ready
  #pragma unroll
  for (int it = 0; it < 8; it++) {
    float dv = dinv[it * 16 + l15];
    #pragma unroll
    for (int ct = 0; ct < 2; ct++)
      #pragma unroll
      for (int r = 0; r < 4; r++)
        out[((size_t)n * CD + w * 32 + ct * 16 + q4 * 4 + r) * HWD + i0 + it * 16 + l15] =
            acc[it][ct][r] * dv;
  }
}

extern "C" void kernel_launch(void* const* d_in, const int* in_sizes, int n_in,
                              void* d_out, int out_size, void* d_ws, size_t ws_size,
                              hipStream_t stream) {
  (void)in_sizes; (void)n_in; (void)out_size;
  const float* x    = (const float*)d_in[0];
  const float* w1   = (const float*)d_in[1];
  const float* b1   = (const float*)d_in[2];
  const float* w2   = (const float*)d_in[3];
  const float* b2   = (const float*)d_in[4];
  const float* wa   = (const float*)d_in[5];
  const float* ba   = (const float*)d_in[6];
  const float* proj = (const float*)d_in[7];
  float* ws  = (float*)d_ws;
  float* out = (float*)d_out;

  if (ws_size < WS_FLOATS * sizeof(float)) {
    fprintf(stderr, "ENLCA: workspace too small: need %zu, have %zu\n",
            WS_FLOATS * sizeof(float), ws_size);
  }

  short* qpB   = (short*)(ws + OFF_QP);
  short* epB   = (short*)(ws + OFF_EP);
  float* gpF   = ws + OFF_GP;
  float* GF    = ws + OFF_G;
  short* ctxB  = (short*)(ws + OFF_CTXB);
  float* ksumF = ws + OFF_KSUM;
  float* xsumF = ws + OFF_XSUM;
  float* ksumbF= ws + OFF_KSUMB;
  float* xsumbF= ws + OFF_XSUMB;
  float* bmaxF = ws + OFF_BMAX;
  float* sblkF = ws + OFF_SBLK;
  short* w1B   = (short*)(ws + OFF_W1B);
  short* w2B   = (short*)(ws + OFF_W2B);
  short* pB    = (short*)(ws + OFF_PB);

  k_prep<<<32, 256, 0, stream>>>(w1, w2, proj, w1B, w2B, pB);
  k_qkf<<<dim3(128, 16), 256, 0, stream>>>(x, w1B, b1, w2B, b2, pB,
                                           qpB, epB, bmaxF, ksumbF, xsumbF);
  k_ksum<<<8, 256, 0, stream>>>(bmaxF, ksumbF, xsumbF, sblkF, ksumF, xsumF);
  k_g<<<dim3(32, 16), 256, 0, stream>>>(x, epB, sblkF, gpF);
  k_gred<<<1024, 256, 0, stream>>>(gpF, xsumF, GF);
  k_ctx<<<128, 256, 0, stream>>>(GF, wa, ba, ksumF, ctxB);
  k_out<<<dim3(128, 16), 256, 0, stream>>>(qpB, ctxB, ksumF, out);
}